// Round 5
// baseline (338.446 us; speedup 1.0000x reference)
//
#include <hip/hip_runtime.h>

#define H     96    // hidden width of both MLPs
#define NOUT  32    // outputs of both MLPs
#define NSEG  97    // H+1 piecewise-linear segments
#define SENTR 97    // sentinel (all-zero) table row
#define NROW  98    // NSEG + sentinel
#define TPAD  128   // breakpoint array padded to pow2 for branchless search
#define TABF  6208  // floats per table: float4[97][16]

// ---- d_ws float-index layout -------------------------------------------
#define WS_TS_MSG   0          // float[128] sorted breakpoints (+inf pad)
#define WS_TS_SC    128        // float[128]
#define WS_ACS      256        // float4[97][16]  scalar-MLP (A0,C0,A1,C1) [s][j]
#define WS_ACM      6464       // float4[97][16]  msg-MLP    (A0,C0,A1,C1) [s][j]
#define WS_RANK     12672      // int[192]
#define WS_CNT      16384      // int[N]      per-node edge counts
#define WS_BS       116480     // int[512]    block sums
#define WS_BSX      116992     // int[512]    exclusive-scanned block sums
#define WS_OFFS     117504     // int[N+1]    CSR offsets
#define WS_CUR      217856     // int[N]      scatter cursors
#define WS_PAY      317952     // float4[E]   sorted edge payloads

// ---------------------------------------------------------------------------
// P1: breakpoints t_j = -b1_j/w1_j, rank-sort, store sorted(+inf padded)+ranks
// ---------------------------------------------------------------------------
__global__ void build_breakpoints(const float* __restrict__ msg_w1,
                                  const float* __restrict__ msg_b1,
                                  const float* __restrict__ sc_w1,
                                  const float* __restrict__ sc_b1,
                                  float* __restrict__ ws) {
    __shared__ float t[2][H];
    const int tid = threadIdx.x;        // 192 threads
    const int mlp = tid / H;
    const int j   = tid % H;
    if (tid < 2 * H) {
        const float* w1 = mlp ? sc_w1 : msg_w1;
        const float* b1 = mlp ? sc_b1 : msg_b1;
        float w = w1[j], b = b1[j];
        t[mlp][j] = (w == 0.0f) ? __builtin_inff() : (-b / w);
    }
    __syncthreads();
    if (tid < 2 * H) {
        float tj = t[mlp][j];
        int r = 0;
        for (int i = 0; i < H; ++i) {
            float ti = t[mlp][i];
            r += (ti < tj) || (ti == tj && i < j);
        }
        float* ts = ws + (mlp ? WS_TS_SC : WS_TS_MSG);
        ts[r] = tj;
        ((int*)(ws + WS_RANK))[mlp * H + j] = r;
    }
    if (tid < 2 * (TPAD - H)) {
        int m2 = tid / (TPAD - H);
        int p  = tid % (TPAD - H);
        ws[m2 * TPAD + H + p] = __builtin_inff();
    }
}

// ---------------------------------------------------------------------------
// P2: per (segment, mlp): A,C with mlp(x) = A*x + C on that segment.
// Both tables paired-float4: dst[s][k>>1] = (A_even, C_even, A_odd, C_odd)
// ---------------------------------------------------------------------------
__global__ void build_tables(const float* __restrict__ msg_w1,
                             const float* __restrict__ msg_b1,
                             const float* __restrict__ msg_w2,
                             const float* __restrict__ msg_b2,
                             const float* __restrict__ sc_w1,
                             const float* __restrict__ sc_b1,
                             const float* __restrict__ sc_w2,
                             const float* __restrict__ sc_b2,
                             float* __restrict__ ws) {
    const int s   = blockIdx.x;   // 0..96
    const int mlp = blockIdx.y;   // 0 = msg, 1 = sc
    const int k   = threadIdx.x;  // 0..31
    const float* w1 = mlp ? sc_w1 : msg_w1;
    const float* b1 = mlp ? sc_b1 : msg_b1;
    const float* w2 = mlp ? sc_w2 : msg_w2;
    const float* b2 = mlp ? sc_b2 : msg_b2;
    const int* rank = (const int*)(ws + WS_RANK) + mlp * H;
    float A = 0.0f, C = 0.0f;
    for (int j = 0; j < H; ++j) {
        float w = w1[j], b = b1[j];
        int   r = rank[j];
        bool active = (w > 0.0f) ? (r < s)
                    : (w < 0.0f) ? (r >= s)
                                 : (b > 0.0f);
        if (active) {
            float wk = w2[j * NOUT + k];
            A = fmaf(w, wk, A);
            C = fmaf(b, wk, C);
        }
    }
    C += b2[k];
    float* dst = ws + (mlp ? WS_ACS : WS_ACM) + 4 * (s * 16 + (k >> 1)) + 2 * (k & 1);
    dst[0] = A; dst[1] = C;
}

// ---------------------------------------------------------------------------
// Sort pipeline: histogram -> 3-kernel exclusive scan -> scatter payloads
// ---------------------------------------------------------------------------
__global__ void hist_kernel(const int* __restrict__ col, int* __restrict__ cnt,
                            int E) {
    int e = blockIdx.x * blockDim.x + threadIdx.x;
    if (e < E) atomicAdd(&cnt[col[e]], 1);
}

__global__ void block_sums(const int* __restrict__ cnt, int* __restrict__ bs,
                           int N) {
    __shared__ int sh[256];
    int i = blockIdx.x * 256 + threadIdx.x;
    sh[threadIdx.x] = (i < N) ? cnt[i] : 0;
    __syncthreads();
    for (int off = 128; off > 0; off >>= 1) {
        if (threadIdx.x < off) sh[threadIdx.x] += sh[threadIdx.x + off];
        __syncthreads();
    }
    if (threadIdx.x == 0) bs[blockIdx.x] = sh[0];
}

__global__ void scan_bs(const int* __restrict__ bs, int* __restrict__ bsx,
                        int nb) {
    __shared__ int sh[512];
    int t = threadIdx.x;
    int v = (t < nb) ? bs[t] : 0;
    sh[t] = v;
    __syncthreads();
    for (int off = 1; off < 512; off <<= 1) {
        int u = (t >= off) ? sh[t - off] : 0;
        __syncthreads();
        sh[t] += u;
        __syncthreads();
    }
    if (t < nb) bsx[t] = sh[t] - v;   // exclusive
}

__global__ void block_scan(const int* __restrict__ cnt,
                           const int* __restrict__ bsx,
                           int* __restrict__ offs, int* __restrict__ cur,
                           int N, int E) {
    __shared__ int sh[256];
    int t = threadIdx.x;
    int i = blockIdx.x * 256 + t;
    int v = (i < N) ? cnt[i] : 0;
    sh[t] = v;
    __syncthreads();
    for (int off = 1; off < 256; off <<= 1) {
        int u = (t >= off) ? sh[t - off] : 0;
        __syncthreads();
        sh[t] += u;
        __syncthreads();
    }
    int excl = sh[t] - v + bsx[blockIdx.x];
    if (i < N) {
        offs[i] = excl;
        cur[i]  = excl;
        if (i == N - 1) offs[N] = excl + v;   // == E
    }
}

// payload = {x, int(sm | ss<<8), c, s}; rot = [[c,-s],[s,c]] so (c,s) suffice
__global__ __launch_bounds__(256) void scatter_kernel(
    const float* __restrict__ v, const float* __restrict__ rot,
    const int* __restrict__ col, const float* __restrict__ ws,
    int* __restrict__ cur, float4* __restrict__ pay, int E)
{
    __shared__ float ts_m[TPAD], ts_s[TPAD];
    for (int i = threadIdx.x; i < 2 * TPAD; i += blockDim.x) {
        float val = ws[i];
        if (i < TPAD) ts_m[i] = val; else ts_s[i - TPAD] = val;
    }
    __syncthreads();
    int e = blockIdx.x * blockDim.x + threadIdx.x;
    if (e >= E) return;
    float2 vv = *(const float2*)(v + 2 * (size_t)e);
    float  x  = sqrtf(vv.x * vv.x + vv.y * vv.y);
    float4 r  = *(const float4*)(rot + 4 * (size_t)e);
    int    c  = col[e];
    int sm = 0;
    #pragma unroll
    for (int st = 64; st > 0; st >>= 1) if (ts_m[sm + st - 1] < x) sm += st;
    int ss = 0;
    #pragma unroll
    for (int st = 64; st > 0; st >>= 1) if (ts_s[ss + st - 1] < x) ss += st;
    int pos = atomicAdd(&cur[c], 1);
    pay[pos] = make_float4(x, __int_as_float(sm | (ss << 8)), r.x, r.z);
}

// ---------------------------------------------------------------------------
// Gather, fused dual-mode: blockIdx.y = 0 -> scalar outputs, 1 -> rot outputs.
// Wave = node. 16 lanes x 4 edge-slots; lane handles OUTPUT PAIR (2q, 2q+1)
// via one float4 table read. Sentinel row 97 (zeros) absorbs invalid slots.
// LDS = 25088 (table, 98 rows) + 4096 (paybuf) = 29184 B -> 5 blocks/CU.
// ---------------------------------------------------------------------------
__global__ __launch_bounds__(256) void gather_kernel(
    const float4* __restrict__ pay, const int* __restrict__ offs,
    const float* __restrict__ ws, float* __restrict__ out, int N)
{
    __shared__ float4 tabv[NROW * 16];    // 25088 B
    __shared__ float4 paybuf[4][64];      //  4096 B
    const int mode = blockIdx.y;          // 0 = scalar, 1 = rot
    {
        const float4* src = (const float4*)(ws + (mode ? WS_ACM : WS_ACS));
        for (int i = threadIdx.x; i < NROW * 16; i += blockDim.x)
            tabv[i] = (i < NSEG * 16) ? src[i] : make_float4(0.f, 0.f, 0.f, 0.f);
    }
    __syncthreads();

    const int wv   = threadIdx.x >> 6;
    const int lane = threadIdx.x & 63;
    const int node = blockIdx.x * 4 + wv;
    if (node >= N) return;
    const int beg = offs[node], end = offs[node + 1];
    const int q       = lane & 15;
    const int quarter = lane >> 4;
    float4* pb = paybuf[wv];

    const int SENTPK = SENTR | (SENTR << 8);
    float a0 = 0.f, a1 = 0.f, b0 = 0.f, b1 = 0.f;

    if (mode == 0) {
        for (int base = beg; base < end; base += 64) {
            int cnt = end - base; if (cnt > 64) cnt = 64;
            float4 pv = make_float4(0.f, __int_as_float(SENTPK), 0.f, 0.f);
            if (lane < cnt) pv = pay[base + lane];
            pb[lane] = pv;
            __threadfence_block();
            int tmax = (cnt + 3) >> 2;
            int t = 0;
            for (; t + 2 <= tmax; t += 2) {
                float4 p0 = pb[4 * t + quarter];
                float4 p1 = pb[4 * t + 4 + quarter];
                float4 c0 = tabv[(__float_as_int(p0.y) >> 8) * 16 + q];
                float4 c1 = tabv[(__float_as_int(p1.y) >> 8) * 16 + q];
                a0 += fmaf(c0.x, p0.x, c0.y);
                a1 += fmaf(c0.z, p0.x, c0.w);
                b0 += fmaf(c1.x, p1.x, c1.y);
                b1 += fmaf(c1.z, p1.x, c1.w);
            }
            if (t < tmax) {
                float4 p0 = pb[4 * t + quarter];
                float4 c0 = tabv[(__float_as_int(p0.y) >> 8) * 16 + q];
                a0 += fmaf(c0.x, p0.x, c0.y);
                a1 += fmaf(c0.z, p0.x, c0.w);
            }
            __threadfence_block();
        }
    } else {
        for (int base = beg; base < end; base += 64) {
            int cnt = end - base; if (cnt > 64) cnt = 64;
            float4 pv = make_float4(0.f, __int_as_float(SENTPK), 0.f, 0.f);
            if (lane < cnt) pv = pay[base + lane];
            pb[lane] = pv;
            __threadfence_block();
            int tmax = (cnt + 3) >> 2;
            int t = 0;
            for (; t + 2 <= tmax; t += 2) {
                float4 p0 = pb[4 * t + quarter];
                float4 p1 = pb[4 * t + 4 + quarter];
                float4 c0 = tabv[(__float_as_int(p0.y) & 255) * 16 + q];
                float4 c1 = tabv[(__float_as_int(p1.y) & 255) * 16 + q];
                float m00 = fmaf(c0.x, p0.x, c0.y);
                float m01 = fmaf(c0.z, p0.x, c0.w);
                float m10 = fmaf(c1.x, p1.x, c1.y);
                float m11 = fmaf(c1.z, p1.x, c1.w);
                a0 += fmaf(m00, p0.z, m01 * p0.w);
                a1 += fmaf(m01, p0.z, -(m00 * p0.w));
                b0 += fmaf(m10, p1.z, m11 * p1.w);
                b1 += fmaf(m11, p1.z, -(m10 * p1.w));
            }
            if (t < tmax) {
                float4 p0 = pb[4 * t + quarter];
                float4 c0 = tabv[(__float_as_int(p0.y) & 255) * 16 + q];
                float m00 = fmaf(c0.x, p0.x, c0.y);
                float m01 = fmaf(c0.z, p0.x, c0.w);
                a0 += fmaf(m00, p0.z, m01 * p0.w);
                a1 += fmaf(m01, p0.z, -(m00 * p0.w));
            }
            __threadfence_block();
        }
    }

    a0 += b0; a1 += b1;
    a0 += __shfl_xor(a0, 16); a0 += __shfl_xor(a0, 32);
    a1 += __shfl_xor(a1, 16); a1 += __shfl_xor(a1, 32);
    if (quarter == 0) {
        float2* dst = (float2*)(out + (mode ? (size_t)N * 32 : 0)
                                + (size_t)node * 32 + 2 * q);
        *dst = make_float2(a0, a1);
    }
}

extern "C" void kernel_launch(void* const* d_in, const int* in_sizes, int n_in,
                              void* d_out, int out_size, void* d_ws, size_t ws_size,
                              hipStream_t stream) {
    const float* v      = (const float*)d_in[0];
    const float* rot    = (const float*)d_in[1];
    const int*   ei     = (const int*)d_in[2];
    const float* msg_w1 = (const float*)d_in[3];
    const float* msg_b1 = (const float*)d_in[4];
    const float* msg_w2 = (const float*)d_in[5];
    const float* msg_b2 = (const float*)d_in[6];
    const float* sc_w1  = (const float*)d_in[7];
    const float* sc_b1  = (const float*)d_in[8];
    const float* sc_w2  = (const float*)d_in[9];
    const float* sc_b2  = (const float*)d_in[10];

    const int E = in_sizes[0] / 2;    // v is [E,2]
    const int N = out_size / 64;      // out = N*32 scalars + N*32 rot floats

    float* ws  = (float*)d_ws;
    float* out = (float*)d_out;

    build_breakpoints<<<1, 192, 0, stream>>>(msg_w1, msg_b1, sc_w1, sc_b1, ws);
    build_tables<<<dim3(NSEG, 2), NOUT, 0, stream>>>(
        msg_w1, msg_b1, msg_w2, msg_b2, sc_w1, sc_b1, sc_w2, sc_b2, ws);

    int*    cnt  = (int*)(ws + WS_CNT);
    int*    bs   = (int*)(ws + WS_BS);
    int*    bsx  = (int*)(ws + WS_BSX);
    int*    offs = (int*)(ws + WS_OFFS);
    int*    cur  = (int*)(ws + WS_CUR);
    float4* pay  = (float4*)(ws + WS_PAY);

    hipMemsetAsync(cnt, 0, (size_t)N * sizeof(int), stream);
    hist_kernel<<<(E + 255) / 256, 256, 0, stream>>>(ei + E, cnt, E);
    int nb = (N + 255) / 256;
    block_sums<<<nb, 256, 0, stream>>>(cnt, bs, N);
    scan_bs<<<1, 512, 0, stream>>>(bs, bsx, nb);
    block_scan<<<nb, 256, 0, stream>>>(cnt, bsx, offs, cur, N, E);
    scatter_kernel<<<(E + 255) / 256, 256, 0, stream>>>(
        v, rot, ei + E, ws, cur, pay, E);
    gather_kernel<<<dim3((N + 3) / 4, 2), 256, 0, stream>>>(pay, offs, ws, out, N);
}

// Round 6
// 215.408 us; speedup vs baseline: 1.5712x; 1.5712x over previous
//
#include <hip/hip_runtime.h>

#define H     96    // hidden width of both MLPs
#define NOUT  32    // outputs of both MLPs
#define NSEG  97    // H+1 piecewise-linear segments
#define TPAD  128   // breakpoint array padded to pow2 for branchless search
#define TABF  6208  // floats per table

#define NPB_LOG 7
#define NPB     128   // nodes per bucket
#define MAXBK   800   // max buckets (N <= 102400)
#define EPB     8192  // edges per bucket_scatter block
#define CAP     3072  // max bucket size for fast finalize (mean 2048, +10 sigma)
#define NP      12    // CAP / 256 payloads staged per thread

// ---- d_ws float-index layout -------------------------------------------
#define WS_TS_MSG   0          // float[128] sorted breakpoints (+inf pad)
#define WS_TS_SC    128        // float[128]
#define WS_ACS      256        // float2[97][32]  scalar-MLP (A, C+b2) [s][k]
#define WS_ACM      6464       // float4[97][16]  msg-MLP (A0,C0,A1,C1) [s][j]
#define WS_RANK     12672      // int[192]
#define WS_GBH      16384      // int[800]  bucket sizes
#define WS_GBO      17184      // int[800]  bucket offsets (excl scan)
#define WS_GCUR     17984      // int[800]  bucket cursors
#define WS_OFFS     18784      // int[N+1]  CSR offsets
#define WS_PAY      118788     // float4[E] bucket-grouped payloads
// WS_PAY2 = WS_PAY + 4*E     // float4[E] node-sorted payloads (if ws allows)

// ---------------------------------------------------------------------------
// P1: breakpoints t_j = -b1_j/w1_j, rank-sort, store sorted(+inf padded)+ranks
// ---------------------------------------------------------------------------
__global__ void build_breakpoints(const float* __restrict__ msg_w1,
                                  const float* __restrict__ msg_b1,
                                  const float* __restrict__ sc_w1,
                                  const float* __restrict__ sc_b1,
                                  float* __restrict__ ws) {
    __shared__ float t[2][H];
    const int tid = threadIdx.x;        // 192 threads
    const int mlp = tid / H;
    const int j   = tid % H;
    if (tid < 2 * H) {
        const float* w1 = mlp ? sc_w1 : msg_w1;
        const float* b1 = mlp ? sc_b1 : msg_b1;
        float w = w1[j], b = b1[j];
        t[mlp][j] = (w == 0.0f) ? __builtin_inff() : (-b / w);
    }
    __syncthreads();
    if (tid < 2 * H) {
        float tj = t[mlp][j];
        int r = 0;
        for (int i = 0; i < H; ++i) {
            float ti = t[mlp][i];
            r += (ti < tj) || (ti == tj && i < j);
        }
        float* ts = ws + (mlp ? WS_TS_SC : WS_TS_MSG);
        ts[r] = tj;
        ((int*)(ws + WS_RANK))[mlp * H + j] = r;
    }
    if (tid < 2 * (TPAD - H)) {
        int m2 = tid / (TPAD - H);
        int p  = tid % (TPAD - H);
        ws[m2 * TPAD + H + p] = __builtin_inff();
    }
}

// ---------------------------------------------------------------------------
// P2: per (segment, mlp): A,C with mlp(x) = A*x + C on that segment.
// sc  -> ws[WS_ACS + 2*(s*32+k)]           = (A, C+b2)       [s][k] float2
// msg -> ws[WS_ACM + 4*(s*16+j) + 2*comp]  = (A, C+b2)       [s][j] float4
// ---------------------------------------------------------------------------
__global__ void build_tables(const float* __restrict__ msg_w1,
                             const float* __restrict__ msg_b1,
                             const float* __restrict__ msg_w2,
                             const float* __restrict__ msg_b2,
                             const float* __restrict__ sc_w1,
                             const float* __restrict__ sc_b1,
                             const float* __restrict__ sc_w2,
                             const float* __restrict__ sc_b2,
                             float* __restrict__ ws) {
    const int s   = blockIdx.x;   // 0..96
    const int mlp = blockIdx.y;   // 0 = msg, 1 = sc
    const int k   = threadIdx.x;  // 0..31
    const float* w1 = mlp ? sc_w1 : msg_w1;
    const float* b1 = mlp ? sc_b1 : msg_b1;
    const float* w2 = mlp ? sc_w2 : msg_w2;
    const float* b2 = mlp ? sc_b2 : msg_b2;
    const int* rank = (const int*)(ws + WS_RANK) + mlp * H;
    float A = 0.0f, C = 0.0f;
    for (int j = 0; j < H; ++j) {
        float w = w1[j], b = b1[j];
        int   r = rank[j];
        bool active = (w > 0.0f) ? (r < s)
                    : (w < 0.0f) ? (r >= s)
                                 : (b > 0.0f);
        if (active) {
            float wk = w2[j * NOUT + k];
            A = fmaf(w, wk, A);
            C = fmaf(b, wk, C);
        }
    }
    C += b2[k];
    if (mlp) {
        float* dst = ws + WS_ACS + 2 * (s * 32 + k);
        dst[0] = A; dst[1] = C;
    } else {
        float* dst = ws + WS_ACM + 4 * (s * 16 + (k >> 1)) + 2 * (k & 1);
        dst[0] = A; dst[1] = C;
    }
}

// ---------------------------------------------------------------------------
// K1: bucket histogram (LDS-privatized; ~205k global atomics total)
// ---------------------------------------------------------------------------
__global__ __launch_bounds__(256) void bucket_hist(
    const int* __restrict__ col, int* __restrict__ gbh, int E, int NBK)
{
    __shared__ int lcnt[MAXBK];
    for (int i = threadIdx.x; i < MAXBK; i += 256) lcnt[i] = 0;
    __syncthreads();
    for (int e = blockIdx.x * 256 + threadIdx.x; e < E; e += gridDim.x * 256)
        atomicAdd(&lcnt[col[e] >> NPB_LOG], 1);
    __syncthreads();
    for (int i = threadIdx.x; i < NBK; i += 256)
        if (lcnt[i]) atomicAdd(&gbh[i], lcnt[i]);
}

// ---------------------------------------------------------------------------
// K2: exclusive scan of bucket sizes -> gbo, gcur (one block, 1024 threads)
// ---------------------------------------------------------------------------
__global__ void scan_buckets(const int* __restrict__ gbh,
                             int* __restrict__ gbo, int* __restrict__ gcur,
                             int NBK) {
    __shared__ int sh[1024];
    int t = threadIdx.x;
    int v = (t < NBK) ? gbh[t] : 0;
    sh[t] = v;
    __syncthreads();
    for (int off = 1; off < 1024; off <<= 1) {
        int u = (t >= off) ? sh[t - off] : 0;
        __syncthreads();
        sh[t] += u;
        __syncthreads();
    }
    if (t < NBK) { gbo[t] = sh[t] - v; gcur[t] = sh[t] - v; }
}

// ---------------------------------------------------------------------------
// K3: bucket scatter. Per block: local bucket counts -> one atomic per
// (block,bucket) for the base -> payloads written in contiguous runs.
// payload = {x, sm | ss<<8 | (col&127)<<16, c, s}
// ---------------------------------------------------------------------------
__global__ __launch_bounds__(256) void bucket_scatter(
    const float* __restrict__ v, const float* __restrict__ rot,
    const int* __restrict__ col, const float* __restrict__ ws,
    int* __restrict__ gcur, float4* __restrict__ pay, int E, int NBK)
{
    __shared__ float ts_m[TPAD], ts_s[TPAD];
    __shared__ int lcnt[MAXBK], lbase[MAXBK];
    for (int i = threadIdx.x; i < 2 * TPAD; i += 256) {
        float val = ws[i];
        if (i < TPAD) ts_m[i] = val; else ts_s[i - TPAD] = val;
    }
    for (int i = threadIdx.x; i < MAXBK; i += 256) lcnt[i] = 0;
    __syncthreads();
    const int e0 = blockIdx.x * EPB;
    const int e1 = min(e0 + EPB, E);
    for (int e = e0 + threadIdx.x; e < e1; e += 256)
        atomicAdd(&lcnt[col[e] >> NPB_LOG], 1);
    __syncthreads();
    for (int b = threadIdx.x; b < NBK; b += 256) {
        int c = lcnt[b];
        lbase[b] = c ? atomicAdd(&gcur[b], c) : 0;
        lcnt[b] = 0;                       // reuse as cursor
    }
    __syncthreads();
    for (int e = e0 + threadIdx.x; e < e1; e += 256) {
        int    c  = col[e];
        float2 vv = *(const float2*)(v + 2 * (size_t)e);
        float  x  = sqrtf(vv.x * vv.x + vv.y * vv.y);
        float4 r  = *(const float4*)(rot + 4 * (size_t)e);
        int sm = 0;
        #pragma unroll
        for (int st = 64; st > 0; st >>= 1) if (ts_m[sm + st - 1] < x) sm += st;
        int ss = 0;
        #pragma unroll
        for (int st = 64; st > 0; st >>= 1) if (ts_s[ss + st - 1] < x) ss += st;
        int b   = c >> NPB_LOG;
        int pos = lbase[b] + atomicAdd(&lcnt[b], 1);
        pay[pos] = make_float4(x,
            __int_as_float(sm | (ss << 8) | ((c & (NPB - 1)) << 16)),
            r.x, r.z);
    }
}

// ---------------------------------------------------------------------------
// K4: per-bucket finalize. Stage bucket in registers, LDS 128-count/scan
// (writes CSR offs), reorder via LDS buffer, stream out coalesced.
// In-place safe (pay2 may alias pay): all reads consumed before writes.
// ---------------------------------------------------------------------------
__global__ __launch_bounds__(256) void bucket_finalize(
    const float4* __restrict__ pay, float4* __restrict__ pay2,
    const int* __restrict__ gbh, const int* __restrict__ gbo,
    int* __restrict__ offs, int N, int NBK, int E)
{
    __shared__ float4 buf[CAP];                       // 48 KB
    __shared__ int s_cnt[NPB], s_scan[NPB], s_loff[NPB];
    const int b    = blockIdx.x;
    const int tid  = threadIdx.x;
    const int lo   = b << NPB_LOG;
    const int nn   = min(NPB, N - lo);
    const int bbeg = gbo[b];
    const int bsz  = gbh[b];
    if (tid < NPB) s_cnt[tid] = 0;
    __syncthreads();

    if (bsz <= CAP) {
        float4 p[NP];
        int    loc[NP];
        #pragma unroll
        for (int i = 0; i < NP; ++i) {
            int idx = i * 256 + tid;
            loc[i] = -1;
            if (idx < bsz) {
                p[i] = pay[bbeg + idx];
                loc[i] = (__float_as_int(p[i].y) >> 16) & 255;
                atomicAdd(&s_cnt[loc[i]], 1);
            }
        }
        __syncthreads();
        if (tid < NPB) s_scan[tid] = s_cnt[tid];
        __syncthreads();
        for (int off = 1; off < NPB; off <<= 1) {
            int u = (tid < NPB && tid >= off) ? s_scan[tid - off] : 0;
            __syncthreads();
            if (tid < NPB) s_scan[tid] += u;
            __syncthreads();
        }
        if (tid < NPB) s_loff[tid] = s_scan[tid] - s_cnt[tid];
        __syncthreads();
        if (tid < nn) offs[lo + tid] = bbeg + s_loff[tid];
        if (b == NBK - 1 && tid == 0) offs[N] = E;
        if (tid < NPB) s_cnt[tid] = 0;                // reuse as cursor
        __syncthreads();
        #pragma unroll
        for (int i = 0; i < NP; ++i) {
            if (loc[i] >= 0) {
                int pos = s_loff[loc[i]] + atomicAdd(&s_cnt[loc[i]], 1);
                float4 q = p[i];
                q.y = __int_as_float(__float_as_int(q.y) & 0xFFFF);
                buf[pos] = q;
            }
        }
        __syncthreads();
        for (int idx = tid; idx < bsz; idx += 256)
            pay2[bbeg + idx] = buf[idx];
    } else {
        // slow path: needs pay2 != pay (guaranteed when ws is large enough;
        // statistically unreachable for this E/N either way)
        for (int idx = tid; idx < bsz; idx += 256) {
            int l = (__float_as_int(pay[bbeg + idx].y) >> 16) & 255;
            atomicAdd(&s_cnt[l], 1);
        }
        __syncthreads();
        if (tid < NPB) s_scan[tid] = s_cnt[tid];
        __syncthreads();
        for (int off = 1; off < NPB; off <<= 1) {
            int u = (tid < NPB && tid >= off) ? s_scan[tid - off] : 0;
            __syncthreads();
            if (tid < NPB) s_scan[tid] += u;
            __syncthreads();
        }
        if (tid < NPB) s_loff[tid] = s_scan[tid] - s_cnt[tid];
        __syncthreads();
        if (tid < nn) offs[lo + tid] = bbeg + s_loff[tid];
        if (b == NBK - 1 && tid == 0) offs[N] = E;
        if (tid < NPB) s_cnt[tid] = 0;
        __syncthreads();
        for (int idx = tid; idx < bsz; idx += 256) {
            float4 q = pay[bbeg + idx];
            int l = (__float_as_int(q.y) >> 16) & 255;
            int pos = s_loff[l] + atomicAdd(&s_cnt[l], 1);
            q.y = __int_as_float(__float_as_int(q.y) & 0xFFFF);
            pay2[bbeg + pos] = q;
        }
    }
}

// ---------------------------------------------------------------------------
// Gather (R4 structure, proven 126 us): fused dual-mode, wave = node,
// 32 outputs x 2 edge-slots, payload chunk staged in per-wave LDS.
// ---------------------------------------------------------------------------
__global__ __launch_bounds__(256) void gather_kernel(
    const float4* __restrict__ pay, const int* __restrict__ offs,
    const float* __restrict__ ws, float* __restrict__ out, int N)
{
    __shared__ float4 tabv[TABF / 4];     // 24832 B
    __shared__ float4 paybuf[4][64];      //  4096 B
    const int mode = blockIdx.y;          // 0 = scalar, 1 = rot
    {
        const float4* src = (const float4*)(ws + (mode ? WS_ACM : WS_ACS));
        for (int i = threadIdx.x; i < TABF / 4; i += blockDim.x)
            tabv[i] = src[i];
    }
    __syncthreads();

    const int wv   = threadIdx.x >> 6;
    const int lane = threadIdx.x & 63;
    const int node = blockIdx.x * 4 + wv;
    if (node >= N) return;
    const int beg = offs[node], end = offs[node + 1];
    const int k    = lane & 31;
    const int half = lane >> 5;
    float4* pb = paybuf[wv];

    pb[lane] = make_float4(0.f, 0.f, 0.f, 0.f);

    float acc = 0.f, acc2 = 0.f;

    if (mode == 0) {
        const float2* t2 = (const float2*)tabv;
        for (int base = beg; base < end; base += 64) {
            int cnt = end - base; if (cnt > 64) cnt = 64;
            if (lane < cnt) pb[lane] = pay[base + lane];
            __threadfence_block();
            int tmax = (cnt + 1) >> 1;
            int t = 0;
            for (; t + 2 <= tmax; t += 2) {
                int e0 = 2 * t + half, e1 = e0 + 2;
                float4 p0 = pb[e0];
                float4 p1 = pb[e1];
                float2 a0 = t2[(__float_as_int(p0.y) >> 8) * 32 + k];
                float2 a1 = t2[(__float_as_int(p1.y) >> 8) * 32 + k];
                float v0 = fmaf(a0.x, p0.x, a0.y);
                float v1 = fmaf(a1.x, p1.x, a1.y);
                acc  += (e0 < cnt) ? v0 : 0.f;
                acc2 += (e1 < cnt) ? v1 : 0.f;
            }
            if (t < tmax) {
                int e0 = 2 * t + half;
                float4 p0 = pb[e0];
                float2 a0 = t2[(__float_as_int(p0.y) >> 8) * 32 + k];
                float v0 = fmaf(a0.x, p0.x, a0.y);
                acc += (e0 < cnt) ? v0 : 0.f;
            }
            __threadfence_block();
        }
    } else {
        const float4* t4 = tabv;
        const int j = k >> 1, comp = k & 1;
        for (int base = beg; base < end; base += 64) {
            int cnt = end - base; if (cnt > 64) cnt = 64;
            if (lane < cnt) pb[lane] = pay[base + lane];
            __threadfence_block();
            int tmax = (cnt + 1) >> 1;
            int t = 0;
            for (; t + 2 <= tmax; t += 2) {
                int e0 = 2 * t + half, e1 = e0 + 2;
                float4 p0 = pb[e0];
                float4 p1 = pb[e1];
                float4 a0 = t4[(__float_as_int(p0.y) & 255) * 16 + j];
                float4 a1 = t4[(__float_as_int(p1.y) & 255) * 16 + j];
                float m00 = fmaf(a0.x, p0.x, a0.y);
                float m01 = fmaf(a0.z, p0.x, a0.w);
                float m10 = fmaf(a1.x, p1.x, a1.y);
                float m11 = fmaf(a1.z, p1.x, a1.w);
                float v0 = comp ? fmaf(m01, p0.z, -(m00 * p0.w))
                                : fmaf(m00, p0.z, m01 * p0.w);
                float v1 = comp ? fmaf(m11, p1.z, -(m10 * p1.w))
                                : fmaf(m10, p1.z, m11 * p1.w);
                acc  += (e0 < cnt) ? v0 : 0.f;
                acc2 += (e1 < cnt) ? v1 : 0.f;
            }
            if (t < tmax) {
                int e0 = 2 * t + half;
                float4 p0 = pb[e0];
                float4 a0 = t4[(__float_as_int(p0.y) & 255) * 16 + j];
                float m00 = fmaf(a0.x, p0.x, a0.y);
                float m01 = fmaf(a0.z, p0.x, a0.w);
                float v0 = comp ? fmaf(m01, p0.z, -(m00 * p0.w))
                                : fmaf(m00, p0.z, m01 * p0.w);
                acc += (e0 < cnt) ? v0 : 0.f;
            }
            __threadfence_block();
        }
    }

    acc += acc2;
    acc += __shfl_xor(acc, 32, 64);
    if (half == 0) {
        float* dst = out + (mode ? (size_t)N * 32 : 0) + (size_t)node * 32 + k;
        *dst = acc;
    }
}

extern "C" void kernel_launch(void* const* d_in, const int* in_sizes, int n_in,
                              void* d_out, int out_size, void* d_ws, size_t ws_size,
                              hipStream_t stream) {
    const float* v      = (const float*)d_in[0];
    const float* rot    = (const float*)d_in[1];
    const int*   ei     = (const int*)d_in[2];
    const float* msg_w1 = (const float*)d_in[3];
    const float* msg_b1 = (const float*)d_in[4];
    const float* msg_w2 = (const float*)d_in[5];
    const float* msg_b2 = (const float*)d_in[6];
    const float* sc_w1  = (const float*)d_in[7];
    const float* sc_b1  = (const float*)d_in[8];
    const float* sc_w2  = (const float*)d_in[9];
    const float* sc_b2  = (const float*)d_in[10];

    const int E = in_sizes[0] / 2;    // v is [E,2]
    const int N = out_size / 64;      // out = N*32 scalars + N*32 rot floats
    const int NBK = (N + NPB - 1) >> NPB_LOG;   // 782 for N=100000 (<= MAXBK)

    float* ws  = (float*)d_ws;
    float* out = (float*)d_out;

    int*    gbh  = (int*)(ws + WS_GBH);
    int*    gbo  = (int*)(ws + WS_GBO);
    int*    gcur = (int*)(ws + WS_GCUR);
    int*    offs = (int*)(ws + WS_OFFS);
    float4* pay  = (float4*)(ws + WS_PAY);
    size_t  pay2_req = ((size_t)WS_PAY + 8 * (size_t)E) * sizeof(float);
    float4* pay2 = (ws_size >= pay2_req) ? (float4*)(ws + WS_PAY + 4 * (size_t)E)
                                         : pay;   // in-place (fast path is safe)

    build_breakpoints<<<1, 192, 0, stream>>>(msg_w1, msg_b1, sc_w1, sc_b1, ws);
    build_tables<<<dim3(NSEG, 2), NOUT, 0, stream>>>(
        msg_w1, msg_b1, msg_w2, msg_b2, sc_w1, sc_b1, sc_w2, sc_b2, ws);

    hipMemsetAsync(gbh, 0, MAXBK * sizeof(int), stream);
    bucket_hist<<<256, 256, 0, stream>>>(ei + E, gbh, E, NBK);
    scan_buckets<<<1, 1024, 0, stream>>>(gbh, gbo, gcur, NBK);
    bucket_scatter<<<(E + EPB - 1) / EPB, 256, 0, stream>>>(
        v, rot, ei + E, ws, gcur, pay, E, NBK);
    bucket_finalize<<<NBK, 256, 0, stream>>>(pay, pay2, gbh, gbo, offs,
                                             N, NBK, E);
    gather_kernel<<<dim3((N + 3) / 4, 2), 256, 0, stream>>>(pay2, offs, ws, out, N);
}